// Round 1
// baseline (168.099 us; speedup 1.0000x reference)
//
#include <hip/hip_runtime.h>
#include <stdint.h>

typedef unsigned short u16;
typedef __attribute__((ext_vector_type(8))) short shortx8;
typedef __attribute__((ext_vector_type(4))) float floatx4;

#define N_ROWS 8192
#define N_COLS 512
#define KDIM   1024
#define N_CLASSES_MAX 64

__device__ __forceinline__ u16 f2bf(float f) {
    union { float f; uint32_t u; } x; x.f = f;
    uint32_t u = x.u;
    // round-to-nearest-even to bf16
    uint32_t r = (u + 0x7FFFu + ((u >> 16) & 1u)) >> 16;
    return (u16)r;
}

__device__ __forceinline__ void async_copy16(const void* g, void* l) {
    __builtin_amdgcn_global_load_lds(
        (const __attribute__((address_space(1))) void*)g,
        (__attribute__((address_space(3))) void*)l, 16, 0, 0);
}

// ---------------- kernel 1: h fp32 -> bf16, row sum of squares ----------------
__global__ __launch_bounds__(256) void conv_h(const float* __restrict__ h,
                                              u16* __restrict__ hb,
                                              float* __restrict__ hsq) {
    int row = blockIdx.x;
    int t = threadIdx.x;
    int lane = t & 63, w = t >> 6;
    const float4* src = (const float4*)(h + (size_t)row * KDIM);
    float4 v = src[t];
    float s = v.x * v.x + v.y * v.y + v.z * v.z + v.w * v.w;
    ushort4 o = make_ushort4(f2bf(v.x), f2bf(v.y), f2bf(v.z), f2bf(v.w));
    ((ushort4*)(hb + (size_t)row * KDIM))[t] = o;
    #pragma unroll
    for (int off = 32; off; off >>= 1) s += __shfl_xor(s, off);
    __shared__ float red[4];
    if (lane == 0) red[w] = s;
    __syncthreads();
    if (t == 0) hsq[row] = red[0] + red[1] + red[2] + red[3];
}

// ------------- kernel 2: protos -> bf16 B[c][k] (pr||pi), |p|^2 --------------
__global__ __launch_bounds__(256) void conv_p(const float* __restrict__ protos,
                                              u16* __restrict__ bb,
                                              float* __restrict__ psq) {
    int c = blockIdx.x;
    int t = threadIdx.x;
    int lane = t & 63, w = t >> 6;
    const float2 pr = ((const float2*)(protos + (size_t)c * 512))[t];
    const float2 pi = ((const float2*)(protos + 512 * 512 + (size_t)c * 512))[t];
    ((ushort2*)(bb + (size_t)c * KDIM))[t]       = make_ushort2(f2bf(pr.x), f2bf(pr.y));
    ((ushort2*)(bb + (size_t)c * KDIM + 512))[t] = make_ushort2(f2bf(pi.x), f2bf(pi.y));
    float s = pr.x * pr.x + pr.y * pr.y + pi.x * pi.x + pi.y * pi.y;
    #pragma unroll
    for (int off = 32; off; off >>= 1) s += __shfl_xor(s, off);
    __shared__ float red[4];
    if (lane == 0) red[w] = s;
    __syncthreads();
    if (t == 0) psq[c] = red[0] + red[1] + red[2] + red[3];
}

// ---------------- kernel 3: bf16 MFMA GEMM + fused logits epilogue -----------
// A = hb [8192][1024], B = bb [512][1024] (both K-contiguous, NT gemm)
// tile 128x128, BK=32, 256 threads (4 waves in 2x2), 16x16x32 bf16 MFMA
__global__ __launch_bounds__(256) void gemm_logits(const u16* __restrict__ hb,
                                                   const u16* __restrict__ bb,
                                                   const float* __restrict__ hsq,
                                                   const float* __restrict__ psq,
                                                   const float* __restrict__ radii,
                                                   float* __restrict__ logits) {
    constexpr int BM = 128, BN = 128, BK = 32;
    __shared__ __align__(16) u16 As[BM * BK];
    __shared__ __align__(16) u16 Bs[BN * BK];

    int t = threadIdx.x;
    int lane = t & 63, w = t >> 6;
    int wr = (w & 1) * 64;      // wave row offset in tile
    int wc = (w >> 1) * 64;     // wave col offset in tile
    int bm0 = blockIdx.x * BM;
    int bn0 = blockIdx.y * BN;

    // staging: thread t loads A[row=t/4][k=(t%3)*8 ..+7] (16B) per chunk
    int srow = t >> 2;
    int scol = (t & 3) * 8;
    const u16* gA0 = hb + (size_t)(bm0 + srow) * KDIM + scol;
    const u16* gA1 = hb + (size_t)(bm0 + 64 + srow) * KDIM + scol;
    const u16* gB0 = bb + (size_t)(bn0 + srow) * KDIM + scol;
    const u16* gB1 = bb + (size_t)(bn0 + 64 + srow) * KDIM + scol;
    u16* lA0 = &As[srow * BK + scol];
    u16* lA1 = &As[(srow + 64) * BK + scol];
    u16* lB0 = &Bs[srow * BK + scol];
    u16* lB1 = &Bs[(srow + 64) * BK + scol];

    floatx4 acc[4][4] = {};

    // fragment base pointers: A[m=lane&15][k=(lane>>4)*8 + j]
    const u16* pa = &As[(wr + (lane & 15)) * BK + (lane >> 4) * 8];
    const u16* pb = &Bs[(wc + (lane & 15)) * BK + (lane >> 4) * 8];

    for (int k0 = 0; k0 < KDIM; k0 += BK) {
        __syncthreads();
        async_copy16(gA0, lA0);
        async_copy16(gA1, lA1);
        async_copy16(gB0, lB0);
        async_copy16(gB1, lB1);
        gA0 += BK; gA1 += BK; gB0 += BK; gB1 += BK;
        __syncthreads();

        shortx8 af[4], bf[4];
        #pragma unroll
        for (int i = 0; i < 4; i++) af[i] = *(const shortx8*)(pa + i * 16 * BK);
        #pragma unroll
        for (int j = 0; j < 4; j++) bf[j] = *(const shortx8*)(pb + j * 16 * BK);
        #pragma unroll
        for (int i = 0; i < 4; i++)
            #pragma unroll
            for (int j = 0; j < 4; j++)
                acc[i][j] = __builtin_amdgcn_mfma_f32_16x16x32_bf16(af[i], bf[j], acc[i][j], 0, 0, 0);
    }

    // epilogue: logits = (2*cross - |h|^2 - |p|^2) / (2*radii)
    // C/D layout: col = lane&15, row = (lane>>4)*4 + reg   [m89/m91 verified]
    int col0 = lane & 15;
    int rquad = (lane >> 4) * 4;
    #pragma unroll
    for (int j = 0; j < 4; j++) {
        int c = bn0 + wc + j * 16 + col0;
        float ps = psq[c];
        float inv = 0.5f / radii[c];
        #pragma unroll
        for (int i = 0; i < 4; i++) {
            int rbase = bm0 + wr + i * 16 + rquad;
            #pragma unroll
            for (int r = 0; r < 4; r++) {
                int n = rbase + r;
                float cross = acc[i][j][r];
                logits[(size_t)n * N_COLS + c] = (2.0f * cross - hsq[n] - ps) * inv;
            }
        }
    }
}

// ---------------- kernel 4: per-row softmax/argmax reductions ----------------
__global__ __launch_bounds__(256) void row_reduce(const float* __restrict__ logits,
                                                  const int* __restrict__ y,
                                                  const int* __restrict__ slab,
                                                  const int* __restrict__ ninit_p,
                                                  float* __restrict__ out) {
    int t = threadIdx.x, lane = t & 63, w = t >> 6;
    int row = blockIdx.x * 4 + w;
    int ninit = ninit_p[0];
    int yv = y[row];
    int lab = (yv >= ninit) ? -1 : yv;
    int slab0 = slab[0];
    const float* lr = logits + (size_t)row * N_COLS;

    float l[8];
    float gmax = -INFINITY; int gidx = 0x7fffffff;
    float rmax = -INFINITY; int ridx = 0x7fffffff;
    float c0max = -INFINITY;
    #pragma unroll
    for (int jj = 0; jj < 8; jj++) {
        int c = lane + jj * 64;
        float v = lr[c];
        int s = slab[c];
        l[jj] = v;
        if (v > gmax) { gmax = v; gidx = c; }
        if (s == lab && v > rmax) { rmax = v; ridx = c; }
        if (s == slab0 && v > c0max) c0max = v;
    }
    #pragma unroll
    for (int off = 32; off; off >>= 1) {
        float ov = __shfl_xor(gmax, off); int oi = __shfl_xor(gidx, off);
        if (ov > gmax || (ov == gmax && oi < gidx)) { gmax = ov; gidx = oi; }
        float orv = __shfl_xor(rmax, off); int ori = __shfl_xor(ridx, off);
        if (orv > rmax || (orv == rmax && ori < ridx)) { rmax = orv; ridx = ori; }
        float oc = __shfl_xor(c0max, off);
        if (oc > c0max) c0max = oc;
    }
    float s = 0.0f;
    #pragma unroll
    for (int jj = 0; jj < 8; jj++) s += __expf(l[jj] - gmax);
    #pragma unroll
    for (int off = 32; off; off >>= 1) s += __shfl_xor(s, off);

    __shared__ float pl[4];
    __shared__ float pa_[4];
    if (lane == 0) {
        float lse = gmax + __logf(s);
        float nll, wgt;
        if (ridx != 0x7fffffff) {           // label group present: w == 1 exactly
            nll = lse - rmax; wgt = 1.0f;
        } else {                            // argmax(all -inf) -> index 0
            float l0 = lr[0];
            nll = lse - l0;
            wgt = (l0 == c0max) ? 1.0f : 0.0f;
        }
        int ypred = slab[gidx];
        float match = (ypred == lab) ? 1.0f : 0.0f;
        pl[w]  = nll * wgt * (1.0f / (float)N_ROWS);
        pa_[w] = match;
    }
    __syncthreads();
    if (t == 0) {
        atomicAdd(&out[0], pl[0] + pl[1] + pl[2] + pl[3]);
        atomicAdd(&out[1], pa_[0] + pa_[1] + pa_[2] + pa_[3]);
    }
}

extern "C" void kernel_launch(void* const* d_in, const int* in_sizes, int n_in,
                              void* d_out, int out_size, void* d_ws, size_t ws_size,
                              hipStream_t stream) {
    const float* h      = (const float*)d_in[0];
    const float* protos = (const float*)d_in[1];
    const float* radii  = (const float*)d_in[2];
    const int*   y      = (const int*)d_in[3];
    const int*   slab   = (const int*)d_in[4];
    const int*   ninit  = (const int*)d_in[5];
    float* out = (float*)d_out;

    char* ws = (char*)d_ws;
    u16*   hb     = (u16*)(ws);                          // 8192*1024*2 = 16 MiB
    u16*   bb     = (u16*)(ws + 16777216);               // 512*1024*2  = 1 MiB
    float* hsq    = (float*)(ws + 17825792);             // 8192*4
    float* psq    = (float*)(ws + 17858560);             // 512*4
    float* logits = (float*)(ws + 17860608);             // 8192*512*4 = 16 MiB

    hipMemsetAsync(d_out, 0, 2 * sizeof(float), stream);

    conv_h<<<N_ROWS, 256, 0, stream>>>(h, hb, hsq);
    conv_p<<<N_COLS, 256, 0, stream>>>(protos, bb, psq);
    dim3 g(N_ROWS / 128, N_COLS / 128);
    gemm_logits<<<g, 256, 0, stream>>>(hb, bb, hsq, psq, radii, logits);
    row_reduce<<<N_ROWS / 4, 256, 0, stream>>>(logits, y, slab, ninit, out);
}

// Round 2
// 131.890 us; speedup vs baseline: 1.2745x; 1.2745x over previous
//
#include <hip/hip_runtime.h>
#include <stdint.h>

typedef unsigned short u16;
typedef __attribute__((ext_vector_type(8))) short shortx8;
typedef __attribute__((ext_vector_type(4))) float floatx4;

#define N_ROWS 8192
#define N_COLS 512
#define KDIM   1024

__device__ __forceinline__ u16 f2bf(float f) {
    union { float f; uint32_t u; } x; x.f = f;
    uint32_t u = x.u;
    uint32_t r = (u + 0x7FFFu + ((u >> 16) & 1u)) >> 16;  // RNE
    return (u16)r;
}

__device__ __forceinline__ void async_copy16(const void* g, void* l) {
    __builtin_amdgcn_global_load_lds(
        (const __attribute__((address_space(1))) void*)g,
        (__attribute__((address_space(3))) void*)l, 16, 0, 0);
}

// -------- kernel 1: h fp32 -> bf16 + row |h|^2. wave-per-row, 4 rows/wave ----
__global__ __launch_bounds__(256) void conv_h(const float* __restrict__ h,
                                              u16* __restrict__ hb,
                                              float* __restrict__ hsq) {
    int t = threadIdx.x, lane = t & 63, w = t >> 6;
    int wave = blockIdx.x * 4 + w;             // 0..2047
    for (int q = 0; q < 4; q++) {
        int row = wave * 4 + q;
        const float4* src = (const float4*)(h + (size_t)row * KDIM);
        ushort4* dst = (ushort4*)(hb + (size_t)row * KDIM);
        float s = 0.0f;
        #pragma unroll
        for (int j = 0; j < 4; j++) {
            float4 v = src[lane + j * 64];
            s += v.x * v.x + v.y * v.y + v.z * v.z + v.w * v.w;
            dst[lane + j * 64] = make_ushort4(f2bf(v.x), f2bf(v.y), f2bf(v.z), f2bf(v.w));
        }
        #pragma unroll
        for (int off = 32; off; off >>= 1) s += __shfl_xor(s, off);
        if (lane == 0) hsq[row] = s;
    }
}

// -------- kernel 2: protos -> bf16 B[c][k]=(pr||pi) + |p|^2. wave-per-class --
__global__ __launch_bounds__(256) void conv_p(const float* __restrict__ protos,
                                              u16* __restrict__ bb,
                                              float* __restrict__ psq) {
    int t = threadIdx.x, lane = t & 63, w = t >> 6;
    int c = blockIdx.x * 4 + w;                // 0..511
    const float4* pr = (const float4*)(protos + (size_t)c * 512);
    const float4* pi = (const float4*)(protos + 512 * 512 + (size_t)c * 512);
    ushort4* dr = (ushort4*)(bb + (size_t)c * KDIM);
    ushort4* di = (ushort4*)(bb + (size_t)c * KDIM + 512);
    float s = 0.0f;
    #pragma unroll
    for (int j = 0; j < 2; j++) {
        float4 a = pr[lane + j * 64];
        float4 b = pi[lane + j * 64];
        s += a.x * a.x + a.y * a.y + a.z * a.z + a.w * a.w;
        s += b.x * b.x + b.y * b.y + b.z * b.z + b.w * b.w;
        dr[lane + j * 64] = make_ushort4(f2bf(a.x), f2bf(a.y), f2bf(a.z), f2bf(a.w));
        di[lane + j * 64] = make_ushort4(f2bf(b.x), f2bf(b.y), f2bf(b.z), f2bf(b.w));
    }
    #pragma unroll
    for (int off = 32; off; off >>= 1) s += __shfl_xor(s, off);
    if (lane == 0) psq[c] = s;
}

// -------- kernel 3: bf16 MFMA GEMM + fused logits epilogue -------------------
// 128x128 tile, BK=64, 512 threads (8 waves, 2x4 -> each wave 64x32).
// LDS k-chunks XOR-swizzled (applied on the GLOBAL source address, since
// global_load_lds lands at base+lane*16 by hardware rule).
__global__ __launch_bounds__(512) void gemm_logits(const u16* __restrict__ hb,
                                                   const u16* __restrict__ bb,
                                                   const float* __restrict__ hsq,
                                                   const float* __restrict__ psq,
                                                   const float* __restrict__ radii,
                                                   float* __restrict__ logits) {
    constexpr int BM = 128, BN = 128, BK = 64;
    __shared__ __align__(16) u16 As[BM * BK];   // 16 KiB
    __shared__ __align__(16) u16 Bs[BN * BK];   // 16 KiB

    int t = threadIdx.x, lane = t & 63, w = t >> 6;
    int wr = (w & 1) * 64;          // wave row offset
    int wc = (w >> 1) * 32;         // wave col offset (4 col-groups of 32)
    int bm0 = blockIdx.x * BM;
    int bn0 = blockIdx.y * BN;

    // staging: thread t owns 16B slots t and t+512 of each of As/Bs.
    // slot s: row = s>>3, stored kchunk = s&7 holds GLOBAL kchunk (s&7)^(row&7)
    int srow = t >> 3;                       // 0..63
    int kcg  = (t & 7) ^ (srow & 7);         // swizzled global k-chunk
    const u16* gA0 = hb + (size_t)(bm0 + srow) * KDIM + kcg * 8;
    const u16* gA1 = gA0 + (size_t)64 * KDIM;
    const u16* gB0 = bb + (size_t)(bn0 + srow) * KDIM + kcg * 8;
    const u16* gB1 = gB0 + (size_t)64 * KDIM;
    u16* lA0 = &As[t * 8]; u16* lA1 = &As[t * 8 + 4096];
    u16* lB0 = &Bs[t * 8]; u16* lB1 = &Bs[t * 8 + 4096];

    floatx4 acc[4][2] = {};

    int kq = lane >> 4, l7 = lane & 7, m = lane & 15;
    // fragment LDS offsets (k-invariant): chunk K = s*4+kq at row R lives at
    // column-chunk K^(R&7); R&7 == l7 for all our rows.
    int swz0 = ((kq) ^ l7) * 8;
    int swz1 = ((4 + kq) ^ l7) * 8;
    const u16* paA = &As[(wr + m) * BK];
    const u16* paB = &Bs[(wc + m) * BK];

    for (int k0 = 0; k0 < KDIM; k0 += BK) {
        __syncthreads();
        async_copy16(gA0, lA0);
        async_copy16(gA1, lA1);
        async_copy16(gB0, lB0);
        async_copy16(gB1, lB1);
        gA0 += BK; gA1 += BK; gB0 += BK; gB1 += BK;
        __syncthreads();

        #pragma unroll
        for (int s = 0; s < 2; s++) {
            int sw = s ? swz1 : swz0;
            shortx8 af[4], bf[2];
            #pragma unroll
            for (int i = 0; i < 4; i++) af[i] = *(const shortx8*)(paA + i * 16 * BK + sw);
            #pragma unroll
            for (int j = 0; j < 2; j++) bf[j] = *(const shortx8*)(paB + j * 16 * BK + sw);
            #pragma unroll
            for (int i = 0; i < 4; i++)
                #pragma unroll
                for (int j = 0; j < 2; j++)
                    acc[i][j] = __builtin_amdgcn_mfma_f32_16x16x32_bf16(af[i], bf[j], acc[i][j], 0, 0, 0);
        }
    }

    // epilogue: logits = (2*cross - |h|^2 - |p|^2) / (2*radii)
    // C/D: col = lane&15, row = (lane>>4)*4 + reg
    #pragma unroll
    for (int j = 0; j < 2; j++) {
        int c = bn0 + wc + j * 16 + m;
        float ps = psq[c];
        float inv = 0.5f / radii[c];
        #pragma unroll
        for (int i = 0; i < 4; i++) {
            int rbase = bm0 + wr + i * 16 + kq * 4;
            #pragma unroll
            for (int r = 0; r < 4; r++) {
                int n = rbase + r;
                logits[(size_t)n * N_COLS + c] = (2.0f * acc[i][j][r] - hsq[n] - ps) * inv;
            }
        }
    }
}

// -------- kernel 4: per-row softmax/argmax, 4 rows/wave, 1 atomic pair/block -
__global__ __launch_bounds__(256) void row_reduce(const float* __restrict__ logits,
                                                  const int* __restrict__ y,
                                                  const int* __restrict__ slab,
                                                  const int* __restrict__ ninit_p,
                                                  float* __restrict__ out) {
    int t = threadIdx.x, lane = t & 63, w = t >> 6;
    int wave = blockIdx.x * 4 + w;             // 0..2047
    int ninit = ninit_p[0];
    int slab0 = slab[0];

    int s8[8];                                  // lane owns cols [lane*8, +8)
    #pragma unroll
    for (int k = 0; k < 8; k++) s8[k] = slab[lane * 8 + k];

    float loss_acc = 0.0f, acc_acc = 0.0f;      // lane0-resident

    for (int q = 0; q < 4; q++) {
        int row = wave * 4 + q;
        int yv = y[row];
        int lab = (yv >= ninit) ? -1 : yv;
        const float4* lr = (const float4*)(logits + (size_t)row * N_COLS);
        float4 v0 = lr[lane * 2], v1 = lr[lane * 2 + 1];
        float l[8] = {v0.x, v0.y, v0.z, v0.w, v1.x, v1.y, v1.z, v1.w};

        float gmax = -INFINITY; int gidx = 0x7fffffff;
        float rmax = -INFINITY; int ridx = 0x7fffffff;
        float c0max = -INFINITY;
        #pragma unroll
        for (int k = 0; k < 8; k++) {
            int c = lane * 8 + k;
            float v = l[k];
            if (v > gmax) { gmax = v; gidx = c; }
            if (s8[k] == lab && v > rmax) { rmax = v; ridx = c; }
            if (s8[k] == slab0 && v > c0max) c0max = v;
        }
        #pragma unroll
        for (int off = 32; off; off >>= 1) {
            float ov = __shfl_xor(gmax, off); int oi = __shfl_xor(gidx, off);
            if (ov > gmax || (ov == gmax && oi < gidx)) { gmax = ov; gidx = oi; }
            float orv = __shfl_xor(rmax, off); int ori = __shfl_xor(ridx, off);
            if (orv > rmax || (orv == rmax && ori < ridx)) { rmax = orv; ridx = ori; }
            float oc = __shfl_xor(c0max, off);
            if (oc > c0max) c0max = oc;
        }
        float s = 0.0f;
        #pragma unroll
        for (int k = 0; k < 8; k++) s += __expf(l[k] - gmax);
        #pragma unroll
        for (int off = 32; off; off >>= 1) s += __shfl_xor(s, off);

        if (lane == 0) {
            float lse = gmax + __logf(s);
            float nll, wgt;
            if (ridx != 0x7fffffff) {            // label group present: w==1
                nll = lse - rmax; wgt = 1.0f;
            } else {                             // argmax over all -inf -> 0
                float l0 = __shfl(l[0], 0);      // logits[row][0] (lane0's l[0])
                nll = lse - l0;
                wgt = (l0 == c0max) ? 1.0f : 0.0f;
            }
            int ypred = (gidx == 0x7fffffff) ? slab0 : 0;  // placeholder, fixed below
            (void)ypred;
            float match = 0.0f;
            // gidx always valid (finite logits)
            match = (s8[0] == lab) ? 0.0f : 0.0f; // placeholder
            loss_acc += nll * wgt;
            acc_acc  += 0.0f;                     // placeholder, real below
            // real pred-match: need slab[gidx]; gidx may belong to another lane.
        }
        // slab[gidx]: fetch uniformly (gidx identical on all lanes post-reduce)
        int ypred = slab[gidx];
        if (lane == 0) acc_acc += (ypred == lab) ? 1.0f : 0.0f;
    }

    __shared__ float pl[4], pa_[4];
    if (lane == 0) { pl[w] = loss_acc * (1.0f / (float)N_ROWS); pa_[w] = acc_acc; }
    __syncthreads();
    if (t == 0) {
        atomicAdd(&out[0], pl[0] + pl[1] + pl[2] + pl[3]);
        atomicAdd(&out[1], pa_[0] + pa_[1] + pa_[2] + pa_[3]);
    }
}

extern "C" void kernel_launch(void* const* d_in, const int* in_sizes, int n_in,
                              void* d_out, int out_size, void* d_ws, size_t ws_size,
                              hipStream_t stream) {
    const float* h      = (const float*)d_in[0];
    const float* protos = (const float*)d_in[1];
    const float* radii  = (const float*)d_in[2];
    const int*   y      = (const int*)d_in[3];
    const int*   slab   = (const int*)d_in[4];
    const int*   ninit  = (const int*)d_in[5];
    float* out = (float*)d_out;

    char* ws = (char*)d_ws;
    u16*   hb     = (u16*)(ws);                          // 16 MiB
    u16*   bb     = (u16*)(ws + 16777216);               // 1 MiB
    float* hsq    = (float*)(ws + 17825792);
    float* psq    = (float*)(ws + 17858560);
    float* logits = (float*)(ws + 17860608);             // 16 MiB

    hipMemsetAsync(d_out, 0, 2 * sizeof(float), stream);

    conv_h<<<512, 256, 0, stream>>>(h, hb, hsq);
    conv_p<<<128, 256, 0, stream>>>(protos, bb, psq);
    dim3 g(N_ROWS / 128, N_COLS / 128);
    gemm_logits<<<g, dim3(512), 0, stream>>>(hb, bb, hsq, psq, radii, logits);
    row_reduce<<<512, 256, 0, stream>>>(logits, y, slab, ninit, out);
}

// Round 3
// 125.842 us; speedup vs baseline: 1.3358x; 1.0481x over previous
//
#include <hip/hip_runtime.h>
#include <stdint.h>

typedef unsigned short u16;
typedef __attribute__((ext_vector_type(8))) short shortx8;
typedef __attribute__((ext_vector_type(4))) float floatx4;

#define N_ROWS 8192
#define N_COLS 512
#define KDIM   1024

__device__ __forceinline__ u16 f2bf(float f) {
    union { float f; uint32_t u; } x; x.f = f;
    uint32_t u = x.u;
    uint32_t r = (u + 0x7FFFu + ((u >> 16) & 1u)) >> 16;  // RNE
    return (u16)r;
}

__device__ __forceinline__ void async_copy16(const void* g, void* l) {
    __builtin_amdgcn_global_load_lds(
        (const __attribute__((address_space(1))) void*)g,
        (__attribute__((address_space(3))) void*)l, 16, 0, 0);
}

// ---- kernel 1: fused input prep --------------------------------------------
// blocks [0,512): h fp32->bf16 + row |h|^2 (wave-per-row, 4 rows/wave)
// blocks [512,640): protos->bf16 B[c][k]=(pr||pi) + |p|^2 (wave-per-class)
__global__ __launch_bounds__(256) void conv_hp(const float* __restrict__ h,
                                               const float* __restrict__ protos,
                                               u16* __restrict__ hb,
                                               u16* __restrict__ bb,
                                               float* __restrict__ hsq,
                                               float* __restrict__ psq) {
    int t = threadIdx.x, lane = t & 63, w = t >> 6;
    int bid = blockIdx.x;
    if (bid < 512) {
        int wave = bid * 4 + w;                    // 0..2047
        for (int q = 0; q < 4; q++) {
            int row = wave * 4 + q;
            const float4* src = (const float4*)(h + (size_t)row * KDIM);
            ushort4* dst = (ushort4*)(hb + (size_t)row * KDIM);
            float s = 0.0f;
            #pragma unroll
            for (int j = 0; j < 4; j++) {
                float4 v = src[lane + j * 64];
                s += v.x * v.x + v.y * v.y + v.z * v.z + v.w * v.w;
                dst[lane + j * 64] = make_ushort4(f2bf(v.x), f2bf(v.y), f2bf(v.z), f2bf(v.w));
            }
            #pragma unroll
            for (int off = 32; off; off >>= 1) s += __shfl_xor(s, off);
            if (lane == 0) hsq[row] = s;
        }
    } else {
        int c = (bid - 512) * 4 + w;               // 0..511
        const float4* pr = (const float4*)(protos + (size_t)c * 512);
        const float4* pi = (const float4*)(protos + 512 * 512 + (size_t)c * 512);
        ushort4* dr = (ushort4*)(bb + (size_t)c * KDIM);
        ushort4* di = (ushort4*)(bb + (size_t)c * KDIM + 512);
        float s = 0.0f;
        #pragma unroll
        for (int j = 0; j < 2; j++) {
            float4 a = pr[lane + j * 64];
            float4 b = pi[lane + j * 64];
            s += a.x * a.x + a.y * a.y + a.z * a.z + a.w * a.w;
            s += b.x * b.x + b.y * b.y + b.z * b.z + b.w * b.w;
            dr[lane + j * 64] = make_ushort4(f2bf(a.x), f2bf(a.y), f2bf(a.z), f2bf(a.w));
            di[lane + j * 64] = make_ushort4(f2bf(b.x), f2bf(b.y), f2bf(b.z), f2bf(b.w));
        }
        #pragma unroll
        for (int off = 32; off; off >>= 1) s += __shfl_xor(s, off);
        if (lane == 0) psq[c] = s;
    }
}

// ---- kernel 2: bf16 MFMA GEMM + fused logits epilogue ----------------------
// BM=128, BN=64, BK=64, 256 threads (4 waves, each 64x32). grid 64x8 = 512
// blocks = 2 blocks/CU so one block computes while the other drains barriers.
// LDS k-chunks XOR-swizzled on the GLOBAL source address (global_load_lds
// lands at wave-uniform base + lane*16 by hardware rule).
__global__ __launch_bounds__(256) void gemm_logits(const u16* __restrict__ hb,
                                                   const u16* __restrict__ bb,
                                                   const float* __restrict__ hsq,
                                                   const float* __restrict__ psq,
                                                   const float* __restrict__ radii,
                                                   float* __restrict__ logits) {
    constexpr int BM = 128, BN = 64, BK = 64;
    __shared__ __align__(16) u16 As[BM * BK];   // 16 KiB
    __shared__ __align__(16) u16 Bs[BN * BK];   // 8 KiB

    int t = threadIdx.x, lane = t & 63, w = t >> 6;
    int wr = (w & 1) * 64;          // wave row offset (2 row-groups of 64)
    int wc = (w >> 1) * 32;         // wave col offset (2 col-groups of 32)
    int bm0 = blockIdx.x * BM;
    int bn0 = blockIdx.y * BN;

    // staging slots: slot s -> row = s>>3, stored kchunk (s&7) holds global
    // kchunk (s&7)^(row&7). Thread t owns A slots t+256*i (i<4), B slots
    // t+256*i (i<2). 16B per slot per K-step.
    int tr = t >> 3, tc = t & 7;
    const u16* gA[4]; u16* lA[4];
    #pragma unroll
    for (int i = 0; i < 4; i++) {
        int row = tr + 32 * i;
        int kc = tc ^ (row & 7);
        gA[i] = hb + (size_t)(bm0 + row) * KDIM + kc * 8;
        lA[i] = &As[(t + 256 * i) * 8];
    }
    const u16* gB[2]; u16* lB[2];
    #pragma unroll
    for (int i = 0; i < 2; i++) {
        int row = tr + 32 * i;
        int kc = tc ^ (row & 7);
        gB[i] = bb + (size_t)(bn0 + row) * KDIM + kc * 8;
        lB[i] = &Bs[(t + 256 * i) * 8];
    }

    floatx4 acc[4][2] = {};

    int kq = lane >> 4, l7 = lane & 7, m = lane & 15;
    // fragment LDS chunk offsets (k-invariant): global chunk K at row R is
    // stored at column-chunk K^(R&7); R&7 == l7 for all fragment rows.
    int swz0 = ((kq) ^ l7) * 8;
    int swz1 = ((4 + kq) ^ l7) * 8;
    const u16* paA = &As[(wr + m) * BK];
    const u16* paB = &Bs[(wc + m) * BK];

    for (int k0 = 0; k0 < KDIM; k0 += BK) {
        __syncthreads();
        #pragma unroll
        for (int i = 0; i < 4; i++) async_copy16(gA[i], lA[i]);
        #pragma unroll
        for (int i = 0; i < 2; i++) async_copy16(gB[i], lB[i]);
        #pragma unroll
        for (int i = 0; i < 4; i++) gA[i] += BK;
        #pragma unroll
        for (int i = 0; i < 2; i++) gB[i] += BK;
        __syncthreads();

        #pragma unroll
        for (int s = 0; s < 2; s++) {
            int sw = s ? swz1 : swz0;
            shortx8 af[4], bf[2];
            #pragma unroll
            for (int i = 0; i < 4; i++) af[i] = *(const shortx8*)(paA + i * 16 * BK + sw);
            #pragma unroll
            for (int j = 0; j < 2; j++) bf[j] = *(const shortx8*)(paB + j * 16 * BK + sw);
            #pragma unroll
            for (int i = 0; i < 4; i++)
                #pragma unroll
                for (int j = 0; j < 2; j++)
                    acc[i][j] = __builtin_amdgcn_mfma_f32_16x16x32_bf16(af[i], bf[j], acc[i][j], 0, 0, 0);
        }
    }

    // epilogue: logits = (2*cross - |h|^2 - |p|^2) / (2*radii)
    // C/D: col = lane&15, row = (lane>>4)*4 + reg
    #pragma unroll
    for (int j = 0; j < 2; j++) {
        int c = bn0 + wc + j * 16 + m;
        float ps = psq[c];
        float inv = 0.5f / radii[c];
        #pragma unroll
        for (int i = 0; i < 4; i++) {
            int rbase = bm0 + wr + i * 16 + kq * 4;
            #pragma unroll
            for (int r = 0; r < 4; r++) {
                int n = rbase + r;
                logits[(size_t)n * N_COLS + c] = (2.0f * acc[i][j][r] - hsq[n] - ps) * inv;
            }
        }
    }
}

// ---- kernel 3: per-row softmax/argmax, 4 rows/wave, 1 atomic pair/block ----
__global__ __launch_bounds__(256) void row_reduce(const float* __restrict__ logits,
                                                  const int* __restrict__ y,
                                                  const int* __restrict__ slab,
                                                  const int* __restrict__ ninit_p,
                                                  float* __restrict__ out) {
    int t = threadIdx.x, lane = t & 63, w = t >> 6;
    int wave = blockIdx.x * 4 + w;             // 0..2047
    int ninit = ninit_p[0];
    int slab0 = slab[0];

    int s8[8];                                  // lane owns cols [lane*8, +8)
    #pragma unroll
    for (int k = 0; k < 8; k++) s8[k] = slab[lane * 8 + k];

    float loss_acc = 0.0f, acc_acc = 0.0f;      // lane0-resident

    for (int q = 0; q < 4; q++) {
        int row = wave * 4 + q;
        int yv = y[row];
        int lab = (yv >= ninit) ? -1 : yv;
        const float4* lr = (const float4*)(logits + (size_t)row * N_COLS);
        float4 v0 = lr[lane * 2], v1 = lr[lane * 2 + 1];
        float l[8] = {v0.x, v0.y, v0.z, v0.w, v1.x, v1.y, v1.z, v1.w};

        float gmax = -INFINITY; int gidx = 0x7fffffff;
        float rmax = -INFINITY; int ridx = 0x7fffffff;
        float c0max = -INFINITY;
        #pragma unroll
        for (int k = 0; k < 8; k++) {
            int c = lane * 8 + k;
            float v = l[k];
            if (v > gmax) { gmax = v; gidx = c; }
            if (s8[k] == lab && v > rmax) { rmax = v; ridx = c; }
            if (s8[k] == slab0 && v > c0max) c0max = v;
        }
        #pragma unroll
        for (int off = 32; off; off >>= 1) {
            float ov = __shfl_xor(gmax, off); int oi = __shfl_xor(gidx, off);
            if (ov > gmax || (ov == gmax && oi < gidx)) { gmax = ov; gidx = oi; }
            float orv = __shfl_xor(rmax, off); int ori = __shfl_xor(ridx, off);
            if (orv > rmax || (orv == rmax && ori < ridx)) { rmax = orv; ridx = ori; }
            float oc = __shfl_xor(c0max, off);
            if (oc > c0max) c0max = oc;
        }
        float s = 0.0f;
        #pragma unroll
        for (int k = 0; k < 8; k++) s += __expf(l[k] - gmax);
        #pragma unroll
        for (int off = 32; off; off >>= 1) s += __shfl_xor(s, off);

        int ypred = slab[gidx];                  // gidx uniform post-reduce
        if (lane == 0) {
            float lse = gmax + __logf(s);
            float nll, wgt;
            if (ridx != 0x7fffffff) {            // label group present: w==1
                nll = lse - rmax; wgt = 1.0f;
            } else {                             // argmax over all -inf -> col 0
                float l0 = l[0];                 // lane0 owns col 0
                nll = lse - l0;
                wgt = (l0 == c0max) ? 1.0f : 0.0f;
            }
            loss_acc += nll * wgt;
            acc_acc  += (ypred == lab) ? 1.0f : 0.0f;
        }
    }

    __shared__ float pl[4], pa_[4];
    if (lane == 0) { pl[w] = loss_acc * (1.0f / (float)N_ROWS); pa_[w] = acc_acc; }
    __syncthreads();
    if (t == 0) {
        atomicAdd(&out[0], pl[0] + pl[1] + pl[2] + pl[3]);
        atomicAdd(&out[1], pa_[0] + pa_[1] + pa_[2] + pa_[3]);
    }
}

extern "C" void kernel_launch(void* const* d_in, const int* in_sizes, int n_in,
                              void* d_out, int out_size, void* d_ws, size_t ws_size,
                              hipStream_t stream) {
    const float* h      = (const float*)d_in[0];
    const float* protos = (const float*)d_in[1];
    const float* radii  = (const float*)d_in[2];
    const int*   y      = (const int*)d_in[3];
    const int*   slab   = (const int*)d_in[4];
    const int*   ninit  = (const int*)d_in[5];
    float* out = (float*)d_out;

    char* ws = (char*)d_ws;
    u16*   hb     = (u16*)(ws);                          // 16 MiB
    u16*   bb     = (u16*)(ws + 16777216);               // 1 MiB
    float* hsq    = (float*)(ws + 17825792);
    float* psq    = (float*)(ws + 17858560);
    float* logits = (float*)(ws + 17860608);             // 16 MiB

    hipMemsetAsync(d_out, 0, 2 * sizeof(float), stream);

    conv_hp<<<640, 256, 0, stream>>>(h, protos, hb, bb, hsq, psq);
    dim3 g(N_ROWS / 128, N_COLS / 64);
    gemm_logits<<<g, 256, 0, stream>>>(hb, bb, hsq, psq, radii, logits);
    row_reduce<<<512, 256, 0, stream>>>(logits, y, slab, ninit, out);
}

// Round 4
// 117.361 us; speedup vs baseline: 1.4323x; 1.0723x over previous
//
#include <hip/hip_runtime.h>
#include <stdint.h>

typedef unsigned short u16;
typedef __attribute__((ext_vector_type(8))) short shortx8;
typedef __attribute__((ext_vector_type(4))) float floatx4;

#define N_ROWS 8192
#define N_COLS 512
#define KDIM   1024

__device__ __forceinline__ u16 f2bf(float f) {
    union { float f; uint32_t u; } x; x.f = f;
    uint32_t u = x.u;
    uint32_t r = (u + 0x7FFFu + ((u >> 16) & 1u)) >> 16;  // RNE
    return (u16)r;
}

__device__ __forceinline__ void async_copy16(const void* g, void* l) {
    __builtin_amdgcn_global_load_lds(
        (const __attribute__((address_space(1))) void*)g,
        (__attribute__((address_space(3))) void*)l, 16, 0, 0);
}

// ---- kernel 1: fused input prep --------------------------------------------
// blocks [0,512): h fp32->bf16 + row |h|^2 (wave-per-row, 4 rows/wave)
// blocks [512,640): protos->bf16 B[c][k]=(pr||pi) + |p|^2 (wave-per-class)
__global__ __launch_bounds__(256) void conv_hp(const float* __restrict__ h,
                                               const float* __restrict__ protos,
                                               u16* __restrict__ hb,
                                               u16* __restrict__ bb,
                                               float* __restrict__ hsq,
                                               float* __restrict__ psq) {
    int t = threadIdx.x, lane = t & 63, w = t >> 6;
    int bid = blockIdx.x;
    if (bid < 512) {
        int wave = bid * 4 + w;                    // 0..2047
        for (int q = 0; q < 4; q++) {
            int row = wave * 4 + q;
            const float4* src = (const float4*)(h + (size_t)row * KDIM);
            ushort4* dst = (ushort4*)(hb + (size_t)row * KDIM);
            float s = 0.0f;
            #pragma unroll
            for (int j = 0; j < 4; j++) {
                float4 v = src[lane + j * 64];
                s += v.x * v.x + v.y * v.y + v.z * v.z + v.w * v.w;
                dst[lane + j * 64] = make_ushort4(f2bf(v.x), f2bf(v.y), f2bf(v.z), f2bf(v.w));
            }
            #pragma unroll
            for (int off = 32; off; off >>= 1) s += __shfl_xor(s, off);
            if (lane == 0) hsq[row] = s;
        }
    } else {
        int c = (bid - 512) * 4 + w;               // 0..511
        const float4* pr = (const float4*)(protos + (size_t)c * 512);
        const float4* pi = (const float4*)(protos + 512 * 512 + (size_t)c * 512);
        ushort4* dr = (ushort4*)(bb + (size_t)c * KDIM);
        ushort4* di = (ushort4*)(bb + (size_t)c * KDIM + 512);
        float s = 0.0f;
        #pragma unroll
        for (int j = 0; j < 2; j++) {
            float4 a = pr[lane + j * 64];
            float4 b = pi[lane + j * 64];
            s += a.x * a.x + a.y * a.y + a.z * a.z + a.w * a.w;
            s += b.x * b.x + b.y * b.y + b.z * b.z + b.w * b.w;
            dr[lane + j * 64] = make_ushort4(f2bf(a.x), f2bf(a.y), f2bf(a.z), f2bf(a.w));
            di[lane + j * 64] = make_ushort4(f2bf(b.x), f2bf(b.y), f2bf(b.z), f2bf(b.w));
        }
        #pragma unroll
        for (int off = 32; off; off >>= 1) s += __shfl_xor(s, off);
        if (lane == 0) psq[c] = s;
    }
}

// ---- kernel 2: bf16 MFMA GEMM + fused logits + row-partial reduction -------
// BM=128, BN=64, BK=64, 256 threads (4 waves, each 64x32), grid 64x8 = 512
// blocks = 2 blocks/CU. Instead of writing 16 MB of logits, each block
// reduces its 64 columns to per-row partials (max/argmax, label-restricted
// max, slab0-max, sum-exp) -> 1.3 MB total, combined by a tiny final kernel.
__global__ __launch_bounds__(256) void gemm_partials(const u16* __restrict__ hb,
                                                     const u16* __restrict__ bb,
                                                     const float* __restrict__ hsq,
                                                     const float* __restrict__ psq,
                                                     const float* __restrict__ radii,
                                                     const int* __restrict__ y,
                                                     const int* __restrict__ slab,
                                                     const int* __restrict__ ninit_p,
                                                     float* __restrict__ pmax_g,
                                                     int* __restrict__ pidx_g,
                                                     float* __restrict__ prmax_g,
                                                     float* __restrict__ pc0_g,
                                                     float* __restrict__ psum_g,
                                                     float* __restrict__ l0arr) {
    constexpr int BM = 128, BN = 64, BK = 64;
    __shared__ __align__(16) u16 As[BM * BK];   // 16 KiB
    __shared__ __align__(16) u16 Bs[BN * BK];   // 8 KiB
    __shared__ float smax[2][128];
    __shared__ int   scol[2][128];
    __shared__ float srmx[2][128];
    __shared__ float sc0v[2][128];
    __shared__ float ssum[2][128];

    int t = threadIdx.x, lane = t & 63, w = t >> 6;
    int wr = (w & 1) * 64;          // wave row offset
    int wc = (w >> 1) * 32;         // wave col offset
    int bm0 = blockIdx.x * BM;
    int bn0 = blockIdx.y * BN;

    // staging slots: slot s -> row = s>>3, stored kchunk (s&7) holds global
    // kchunk (s&7)^(row&7).
    int tr = t >> 3, tc = t & 7;
    const u16* gA[4]; u16* lA[4];
    #pragma unroll
    for (int i = 0; i < 4; i++) {
        int row = tr + 32 * i;
        int kc = tc ^ (row & 7);
        gA[i] = hb + (size_t)(bm0 + row) * KDIM + kc * 8;
        lA[i] = &As[(t + 256 * i) * 8];
    }
    const u16* gB[2]; u16* lB[2];
    #pragma unroll
    for (int i = 0; i < 2; i++) {
        int row = tr + 32 * i;
        int kc = tc ^ (row & 7);
        gB[i] = bb + (size_t)(bn0 + row) * KDIM + kc * 8;
        lB[i] = &Bs[(t + 256 * i) * 8];
    }

    floatx4 acc[4][2] = {};

    int kq = lane >> 4, l7 = lane & 7, m = lane & 15;
    int swz0 = ((kq) ^ l7) * 8;
    int swz1 = ((4 + kq) ^ l7) * 8;
    const u16* paA = &As[(wr + m) * BK];
    const u16* paB = &Bs[(wc + m) * BK];

    for (int k0 = 0; k0 < KDIM; k0 += BK) {
        __syncthreads();
        #pragma unroll
        for (int i = 0; i < 4; i++) async_copy16(gA[i], lA[i]);
        #pragma unroll
        for (int i = 0; i < 2; i++) async_copy16(gB[i], lB[i]);
        #pragma unroll
        for (int i = 0; i < 4; i++) gA[i] += BK;
        #pragma unroll
        for (int i = 0; i < 2; i++) gB[i] += BK;
        __syncthreads();

        #pragma unroll
        for (int s = 0; s < 2; s++) {
            int sw = s ? swz1 : swz0;
            shortx8 af[4], bf[2];
            #pragma unroll
            for (int i = 0; i < 4; i++) af[i] = *(const shortx8*)(paA + i * 16 * BK + sw);
            #pragma unroll
            for (int j = 0; j < 2; j++) bf[j] = *(const shortx8*)(paB + j * 16 * BK + sw);
            #pragma unroll
            for (int i = 0; i < 4; i++)
                #pragma unroll
                for (int j = 0; j < 2; j++)
                    acc[i][j] = __builtin_amdgcn_mfma_f32_16x16x32_bf16(af[i], bf[j], acc[i][j], 0, 0, 0);
        }
    }

    // ---- epilogue: logits in-register, reduce 64 cols -> per-row partials --
    // C/D: col = lane&15 (=m), row = kq*4 + reg. Lane's 2 cols:
    int c0 = bn0 + wc + m, c1 = c0 + 16;
    float ps0 = psq[c0], ps1 = psq[c1];
    float inv0 = 0.5f / radii[c0], inv1 = 0.5f / radii[c1];
    int sl0 = slab[c0], sl1 = slab[c1];
    int slabz = slab[0];
    int ninit = ninit_p[0];
    int ch = w >> 1;                 // column half within block
    bool isL0 = (bn0 == 0) && (wc == 0) && (m == 0);

    #pragma unroll
    for (int i = 0; i < 4; i++) {
        #pragma unroll
        for (int r = 0; r < 4; r++) {
            int n = bm0 + wr + i * 16 + kq * 4 + r;
            float hsqn = hsq[n];
            int yv = y[n];
            int lab = (yv >= ninit) ? -1 : yv;
            float v0 = (2.0f * acc[i][0][r] - hsqn - ps0) * inv0;
            float v1 = (2.0f * acc[i][1][r] - hsqn - ps1) * inv1;
            if (isL0) l0arr[n] = v0;                 // logits[n][0]

            float bmax = v0; int bcol = c0;
            if (v1 > bmax) { bmax = v1; bcol = c1; } // tie keeps lower col
            float brm = -INFINITY;
            if (sl0 == lab) brm = v0;
            if (sl1 == lab && v1 > brm) brm = v1;
            float bc0 = -INFINITY;
            if (sl0 == slabz) bc0 = v0;
            if (sl1 == slabz && v1 > bc0) bc0 = v1;
            #pragma unroll
            for (int off = 1; off < 16; off <<= 1) {   // reduce over m (16 lanes)
                float ov = __shfl_xor(bmax, off); int oc = __shfl_xor(bcol, off);
                if (ov > bmax || (ov == bmax && oc < bcol)) { bmax = ov; bcol = oc; }
                float orv = __shfl_xor(brm, off); if (orv > brm) brm = orv;
                float oc0 = __shfl_xor(bc0, off); if (oc0 > bc0) bc0 = oc0;
            }
            float se = __expf(v0 - bmax) + __expf(v1 - bmax);
            #pragma unroll
            for (int off = 1; off < 16; off <<= 1) se += __shfl_xor(se, off);
            if (m == 0) {
                int rl = (w & 1) * 64 + i * 16 + kq * 4 + r;
                smax[ch][rl] = bmax; scol[ch][rl] = bcol;
                srmx[ch][rl] = brm;  sc0v[ch][rl] = bc0; ssum[ch][rl] = se;
            }
        }
    }
    __syncthreads();
    if (t < 128) {                    // merge the two 32-col halves, write
        int n = bm0 + t;
        size_t gi_ = (size_t)blockIdx.y * N_ROWS + n;
        float m0 = smax[0][t], m1 = smax[1][t];
        int i0 = scol[0][t], i1 = scol[1][t];
        float gm; int gi;
        if (m0 > m1 || (m0 == m1 && i0 < i1)) { gm = m0; gi = i0; }
        else { gm = m1; gi = i1; }
        pmax_g[gi_] = gm;
        pidx_g[gi_] = gi;
        prmax_g[gi_] = fmaxf(srmx[0][t], srmx[1][t]);
        pc0_g[gi_]  = fmaxf(sc0v[0][t], sc0v[1][t]);
        psum_g[gi_] = ssum[0][t] * __expf(m0 - gm) + ssum[1][t] * __expf(m1 - gm);
    }
}

// ---- kernel 3: combine 8 column-block partials per row -> loss, acc --------
__global__ __launch_bounds__(256) void combine(const float* __restrict__ pmax_g,
                                               const int* __restrict__ pidx_g,
                                               const float* __restrict__ prmax_g,
                                               const float* __restrict__ pc0_g,
                                               const float* __restrict__ psum_g,
                                               const float* __restrict__ l0arr,
                                               const int* __restrict__ y,
                                               const int* __restrict__ slab,
                                               const int* __restrict__ ninit_p,
                                               float* __restrict__ out) {
    int t = threadIdx.x, lane = t & 63, w = t >> 6;
    int n = blockIdx.x * 256 + t;

    float gm = -INFINITY; int gi = 0x7fffffff;
    float rm = -INFINITY, c0m = -INFINITY;
    float pm[8];
    #pragma unroll
    for (int cb = 0; cb < 8; cb++) {
        size_t idx = (size_t)cb * N_ROWS + n;
        float p = pmax_g[idx]; int pi = pidx_g[idx];
        pm[cb] = p;
        if (p > gm || (p == gm && pi < gi)) { gm = p; gi = pi; }
        rm = fmaxf(rm, prmax_g[idx]);
        c0m = fmaxf(c0m, pc0_g[idx]);
    }
    float den = 0.0f;
    #pragma unroll
    for (int cb = 0; cb < 8; cb++)
        den += psum_g[(size_t)cb * N_ROWS + n] * __expf(pm[cb] - gm);
    float lse = gm + __logf(den);

    int yv = y[n];
    int lab = (yv >= ninit_p[0]) ? -1 : yv;
    float nll, wgt;
    if (rm != -INFINITY) { nll = lse - rm; wgt = 1.0f; }
    else {                                   // all-(-inf) argmax -> col 0
        float l0 = l0arr[n];
        nll = lse - l0;
        wgt = (l0 == c0m) ? 1.0f : 0.0f;
    }
    int ypred = slab[gi];
    float li = nll * wgt * (1.0f / (float)N_ROWS);
    float ai = (ypred == lab) ? 1.0f : 0.0f;

    #pragma unroll
    for (int off = 32; off; off >>= 1) {
        li += __shfl_xor(li, off);
        ai += __shfl_xor(ai, off);
    }
    __shared__ float pl[4], pa_[4];
    if (lane == 0) { pl[w] = li; pa_[w] = ai; }
    __syncthreads();
    if (t == 0) {
        atomicAdd(&out[0], pl[0] + pl[1] + pl[2] + pl[3]);
        atomicAdd(&out[1], pa_[0] + pa_[1] + pa_[2] + pa_[3]);
    }
}

extern "C" void kernel_launch(void* const* d_in, const int* in_sizes, int n_in,
                              void* d_out, int out_size, void* d_ws, size_t ws_size,
                              hipStream_t stream) {
    const float* h      = (const float*)d_in[0];
    const float* protos = (const float*)d_in[1];
    const float* radii  = (const float*)d_in[2];
    const int*   y      = (const int*)d_in[3];
    const int*   slab   = (const int*)d_in[4];
    const int*   ninit  = (const int*)d_in[5];
    float* out = (float*)d_out;

    char* ws = (char*)d_ws;
    u16*   hb    = (u16*)(ws);                       // 16 MiB
    u16*   bb    = (u16*)(ws + 16777216);            // 1 MiB
    float* hsq   = (float*)(ws + 17825792);          // 32 KiB
    float* psq   = (float*)(ws + 17858560);          // 2 KiB
    float* pmax  = (float*)(ws + 17860608);          // 8*8192*4 = 256 KiB
    int*   pidx  = (int*)  (ws + 18122752);
    float* prmax = (float*)(ws + 18384896);
    float* pc0   = (float*)(ws + 18647040);
    float* psum  = (float*)(ws + 18909184);
    float* l0arr = (float*)(ws + 19171328);          // 32 KiB

    hipMemsetAsync(d_out, 0, 2 * sizeof(float), stream);

    conv_hp<<<640, 256, 0, stream>>>(h, protos, hb, bb, hsq, psq);
    dim3 g(N_ROWS / 128, N_COLS / 64);
    gemm_partials<<<g, 256, 0, stream>>>(hb, bb, hsq, psq, radii, y, slab, ninit,
                                         pmax, pidx, prmax, pc0, psum, l0arr);
    combine<<<N_ROWS / 256, 256, 0, stream>>>(pmax, pidx, prmax, pc0, psum,
                                              l0arr, y, slab, ninit, out);
}